// Round 10
// baseline (57.260 us; speedup 1.0000x reference)
//
#include <hip/hip_runtime.h>
#include <hip/hip_bf16.h>
#include <cstddef>
#include <cstdint>

#define CH_HW 4096   // 64*64

typedef __bf16  bf16x8  __attribute__((ext_vector_type(8)));
typedef float   f32x4   __attribute__((ext_vector_type(4)));
typedef unsigned int u32x4 __attribute__((ext_vector_type(4)));

// d_ws layout (fast path):
//   [0, WF)            bf16 offset-conv weight B-frags
//   [WF, +OFFW)        bf16 offset field
//   [WF+OFFW, +DWB)    bf16 deform weight B-frags
//   [WF+OFFW+DWB,+XT)  bf16 plane-major x: xt[b][g][cgrp][pix][c8]  (16B/px)
#define WF_ELEMS 331776                 // 72 ks * 9 nt * 64 lane * 8
#define WF_BYTES (WF_ELEMS * 2)
#define OFFW_BYTES (4u * 144u * CH_HW * 2u)   // 4,718,592
#define DWB_ELEMS (8 * 9 * 2 * 512)
#define DWB_BYTES (DWB_ELEMS * 2)
#define XT_BYTES ((size_t)4 * 8 * CH_HW * 32 * 2)   // 8,388,608

__device__ __forceinline__ u32x4 pack_bf16x8(const float av[8]) {
    u32x4 ad;
#pragma unroll
    for (int jj = 0; jj < 4; ++jj) {
        const unsigned int lo = __builtin_bit_cast(unsigned short, __float2bfloat16(av[2 * jj]));
        const unsigned int hi = __builtin_bit_cast(unsigned short, __float2bfloat16(av[2 * jj + 1]));
        ad[jj] = lo | (hi << 16);
    }
    return ad;
}
__device__ __forceinline__ float bf16lo(unsigned int u) {
    return __builtin_bit_cast(float, u << 16);
}
__device__ __forceinline__ float bf16hi(unsigned int u) {
    return __builtin_bit_cast(float, u & 0xFFFF0000u);
}

// ---------------------------------------------------------------------------
// Kernel 0 (fused prep): y=0 repack_w, y=1 repack_dwb, y=2 xt_pack
// ---------------------------------------------------------------------------
__global__ __launch_bounds__(256) void prep(const float* __restrict__ ow,
                                            const float* __restrict__ dw,
                                            const float* __restrict__ x,
                                            __hip_bfloat16* __restrict__ wf,
                                            __hip_bfloat16* __restrict__ dwb,
                                            __hip_bfloat16* __restrict__ xt)
{
    const int job = blockIdx.y;
    if (job == 0) {
        const int t = blockIdx.x * 256 + threadIdx.x;
        if (t >= WF_ELEMS) return;
        const int j    = t & 7;
        const int lane = (t >> 3) & 63;
        const int tmp  = t >> 9;
        const int nt   = tmp % 9;
        const int ks   = tmp / 9;
        const int tap  = ks >> 3, icb = ks & 7;
        const int oc   = nt * 16 + (lane & 15);
        const int ic   = icb * 32 + (lane >> 4) * 8 + j;
        wf[t] = __float2bfloat16(ow[(size_t)oc * 2304 + ic * 9 + tap]);
    } else if (job == 1) {
        const int t = blockIdx.x * 256 + threadIdx.x;
        if (t >= DWB_ELEMS) return;
        const int j    = t & 7;
        const int lane = (t >> 3) & 63;
        const int nt   = (t >> 9) & 1;
        const int gk   = t >> 10;
        const int k    = gk % 9;
        const int g    = gk / 9;
        const int oc   = g * 32 + nt * 16 + (lane & 15);
        const int c    = (lane >> 4) * 8 + j;
        dwb[t] = __float2bfloat16(dw[(size_t)oc * 288 + c * 9 + k]);
    } else {
        const int bid = blockIdx.x;
        if (bid >= 512) return;
        const int chunk = bid & 15;
        const int g = (bid >> 4) & 7, b = bid >> 7;
        const int pix = (chunk << 8) + threadIdx.x;
        const float* xs = x + ((size_t)b * 256 + g * 32) * CH_HW + pix;
        __hip_bfloat16* xp = xt + ((size_t)b * 8 + g) * 4 * CH_HW * 8;
#pragma unroll
        for (int q = 0; q < 4; ++q) {
            float av[8];
#pragma unroll
            for (int j = 0; j < 8; ++j) av[j] = xs[(size_t)(q * 8 + j) * CH_HW];
            *(u32x4*)(xp + ((size_t)q * CH_HW + pix) * 8) = pack_bf16x8(av);
        }
    }
}

// ---------------------------------------------------------------------------
// Kernel 1 (fast): offset conv MFMA, K-split x4 (18 ks per wave).
// Block = 256 thr = 4 kh-waves over one 32-px M-tile x NT N-frags.
// Grid 1024 = (b x hrow x colhalf x nhalf) -> 4 blocks/CU, 4 waves/SIMD.
// kh 1..3 dump partials to LDS; one barrier; kh0 reduces + stores.
// ---------------------------------------------------------------------------
template<int NT>
__device__ __forceinline__ void offs_body6(
    const __hip_bfloat16* __restrict__ xb,   // xt for image b (plane-major)
    const __hip_bfloat16* __restrict__ wfl,  // wf + (ntBase*64+lane)*8
    const float* __restrict__ ob,
    __hip_bfloat16* __restrict__ offw_b,     // offw for image b
    float* __restrict__ red,                 // LDS: 3 x 2560 floats
    int hrow, int colbase, int lane, int ntBase, int kh)
{
    const int arow = lane & 15, cgrp = lane >> 4;
    const int ks0 = kh * 18;

    auto loadA1 = [&](int ks, int mt) -> u32x4 {
        const int tap = ks >> 3, icb = ks & 7;
        const int dy = tap / 3 - 1, dx = tap % 3 - 1;
        const int sh = hrow + dy, sw = colbase + mt * 16 + arow + dx;
        const bool valid = (sh >= 0) & (sh < 64) & (sw >= 0) & (sw < 64);
        const int spix = (min(max(sh, 0), 63) << 6) + min(max(sw, 0), 63);
        u32x4 a = *(const u32x4*)(xb + ((size_t)(icb * 4 + cgrp) * CH_HW + spix) * 8);
        if (!valid) a = (u32x4){0, 0, 0, 0};
        return a;
    };

    f32x4 acc[2][NT];
#pragma unroll
    for (int mt = 0; mt < 2; ++mt)
#pragma unroll
        for (int nt = 0; nt < NT; ++nt) acc[mt][nt] = (f32x4){0.f, 0.f, 0.f, 0.f};

    u32x4 a0[2], a1[2], b0[NT], b1[NT];
#pragma unroll
    for (int mt = 0; mt < 2; ++mt) {
        a0[mt] = loadA1(ks0 + 0, mt);
        a1[mt] = loadA1(ks0 + 1, mt);
    }
#pragma unroll
    for (int nt = 0; nt < NT; ++nt) {
        b0[nt] = *(const u32x4*)(wfl + (size_t)((ks0 + 0) * 9 + nt) * 512);
        b1[nt] = *(const u32x4*)(wfl + (size_t)((ks0 + 1) * 9 + nt) * 512);
    }

    // 8 branch-free iterations (consume pair i,i+1; refill i+2,i+3)
#pragma unroll 1
    for (int i = 0; i < 16; i += 2) {
        const int ks = ks0 + i;
#pragma unroll
        for (int mt = 0; mt < 2; ++mt) {
            const bf16x8 af = __builtin_bit_cast(bf16x8, a0[mt]);
#pragma unroll
            for (int nt = 0; nt < NT; ++nt)
                acc[mt][nt] = __builtin_amdgcn_mfma_f32_16x16x32_bf16(
                    af, __builtin_bit_cast(bf16x8, b0[nt]), acc[mt][nt], 0, 0, 0);
        }
#pragma unroll
        for (int mt = 0; mt < 2; ++mt) a0[mt] = loadA1(ks + 2, mt);
#pragma unroll
        for (int nt = 0; nt < NT; ++nt)
            b0[nt] = *(const u32x4*)(wfl + (size_t)((ks + 2) * 9 + nt) * 512);
#pragma unroll
        for (int mt = 0; mt < 2; ++mt) {
            const bf16x8 af = __builtin_bit_cast(bf16x8, a1[mt]);
#pragma unroll
            for (int nt = 0; nt < NT; ++nt)
                acc[mt][nt] = __builtin_amdgcn_mfma_f32_16x16x32_bf16(
                    af, __builtin_bit_cast(bf16x8, b1[nt]), acc[mt][nt], 0, 0, 0);
        }
#pragma unroll
        for (int mt = 0; mt < 2; ++mt) a1[mt] = loadA1(ks + 3, mt);
#pragma unroll
        for (int nt = 0; nt < NT; ++nt)
            b1[nt] = *(const u32x4*)(wfl + (size_t)((ks + 3) * 9 + nt) * 512);
    }
    // peeled tail: consume last pair (ks0+16, ks0+17)
#pragma unroll
    for (int mt = 0; mt < 2; ++mt) {
        const bf16x8 af = __builtin_bit_cast(bf16x8, a0[mt]);
#pragma unroll
        for (int nt = 0; nt < NT; ++nt)
            acc[mt][nt] = __builtin_amdgcn_mfma_f32_16x16x32_bf16(
                af, __builtin_bit_cast(bf16x8, b0[nt]), acc[mt][nt], 0, 0, 0);
    }
#pragma unroll
    for (int mt = 0; mt < 2; ++mt) {
        const bf16x8 af = __builtin_bit_cast(bf16x8, a1[mt]);
#pragma unroll
        for (int nt = 0; nt < NT; ++nt)
            acc[mt][nt] = __builtin_amdgcn_mfma_f32_16x16x32_bf16(
                af, __builtin_bit_cast(bf16x8, b1[nt]), acc[mt][nt], 0, 0, 0);
    }

    // 4-way K reduction: kh 1..3 dump, barrier, kh0 reduces + stores
    if (kh > 0) {
        float* r = red + (kh - 1) * 2560;
#pragma unroll
        for (int mt = 0; mt < 2; ++mt)
#pragma unroll
            for (int nt = 0; nt < NT; ++nt)
                *(f32x4*)&r[((mt * NT + nt) * 64 + lane) * 4] = acc[mt][nt];
    }
    __syncthreads();
    if (kh == 0) {
#pragma unroll
        for (int mt = 0; mt < 2; ++mt) {
            const int pxb = hrow * 64 + colbase + mt * 16 + (cgrp << 2);
#pragma unroll
            for (int nt = 0; nt < NT; ++nt) {
                const int ri = ((mt * NT + nt) * 64 + lane) * 4;
                const f32x4 p1 = *(const f32x4*)&red[ri];
                const f32x4 p2 = *(const f32x4*)&red[2560 + ri];
                const f32x4 p3 = *(const f32x4*)&red[5120 + ri];
                const int oc = (ntBase + nt) * 16 + arow;
                const float bias = ob[oc];
                float av[4];
#pragma unroll
                for (int r4 = 0; r4 < 4; ++r4)
                    av[r4] = acc[mt][nt][r4] + p1[r4] + p2[r4] + p3[r4] + bias;
                unsigned int q0 = (unsigned int)__builtin_bit_cast(unsigned short, __float2bfloat16(av[0])) |
                                  ((unsigned int)__builtin_bit_cast(unsigned short, __float2bfloat16(av[1])) << 16);
                unsigned int q1 = (unsigned int)__builtin_bit_cast(unsigned short, __float2bfloat16(av[2])) |
                                  ((unsigned int)__builtin_bit_cast(unsigned short, __float2bfloat16(av[3])) << 16);
                unsigned int* op = (unsigned int*)(offw_b + (size_t)oc * CH_HW + pxb);
                op[0] = q0; op[1] = q1;
            }
        }
    }
}

__global__ __launch_bounds__(256, 4) void offs_mfma6(
    const __hip_bfloat16* __restrict__ xt,
    const __hip_bfloat16* __restrict__ wf,
    const float* __restrict__ ob,
    __hip_bfloat16* __restrict__ offw)
{
    __shared__ float red[7680];               // 3 partial regions x 2560
    const int bid  = blockIdx.x;              // 0..1023
    const int xcd  = bid & 7;
    const int b    = xcd >> 1;                // 2 XCDs per batch image
    const int half = xcd & 1;
    const int flat = half * 128 + (bid >> 3); // 0..255 within image
    const int hrow = flat >> 2;
    const int col  = (flat >> 1) & 1;
    const int nh   = flat & 1;
    const int tid  = threadIdx.x;
    const int lane = tid & 63, kh = tid >> 6;
    const int ntBase = nh * 5;
    const int colbase = col * 32;

    const __hip_bfloat16* xb  = xt + (size_t)b * 8 * CH_HW * 32;
    const __hip_bfloat16* wfl = wf + (size_t)(ntBase * 64 + lane) * 8;
    __hip_bfloat16* offw_b = offw + (size_t)b * 144 * CH_HW;

    if (nh == 0) offs_body6<5>(xb, wfl, ob, offw_b, red, hrow, colbase, lane, ntBase, kh);
    else         offs_body6<4>(xb, wfl, ob, offw_b, red, hrow, colbase, lane, ntBase, kh);
}

// ---------------------------------------------------------------------------
// Kernel 2 (fast): bilinear sampling (plane-major xt, 16B pixel stride) +
// grouped-conv MFMA. 1-D grid XCD-pinned: wgid = pt*32 + (g+8b).
// ---------------------------------------------------------------------------
struct Samp { int iA, iB, iC, iD; float wA, wB, wC, wD; };

__device__ __forceinline__ Samp make_samp(float py, float px) {
    const float y0f = floorf(py), x0f = floorf(px);
    const int iy0 = (int)y0f, ix0 = (int)x0f;
    const int iy1 = iy0 + 1,  ix1 = ix0 + 1;
    const float fy1 = py - y0f, fx1 = px - x0f;
    const float fy0 = 1.f - fy1, fx0 = 1.f - fx1;
    const bool vy0 = (iy0 >= 0) & (iy0 < 64);
    const bool vy1 = (iy1 >= 0) & (iy1 < 64);
    const bool vx0 = (ix0 >= 0) & (ix0 < 64);
    const bool vx1 = (ix1 >= 0) & (ix1 < 64);
    const int cy0 = min(max(iy0, 0), 63), cy1 = min(max(iy1, 0), 63);
    const int cx0 = min(max(ix0, 0), 63), cx1 = min(max(ix1, 0), 63);
    Samp s;
    s.iA = (cy0 << 6) + cx0; s.iB = (cy0 << 6) + cx1;
    s.iC = (cy1 << 6) + cx0; s.iD = (cy1 << 6) + cx1;
    s.wA = (vy0 & vx0) ? fy0 * fx0 : 0.f;
    s.wB = (vy0 & vx1) ? fy0 * fx1 : 0.f;
    s.wC = (vy1 & vx0) ? fy1 * fx0 : 0.f;
    s.wD = (vy1 & vx1) ? fy1 * fx1 : 0.f;
    return s;
}

__global__ __launch_bounds__(256, 4) void deform6(
    const __hip_bfloat16* __restrict__ xt,
    const __hip_bfloat16* __restrict__ offw,
    const __hip_bfloat16* __restrict__ dwb,
    const float* __restrict__ db,
    float* __restrict__ out)
{
    const int bid  = blockIdx.x;        // 0..2047
    const int pair = bid & 31;          // g + 8*b  -> XCD = pair % 8
    const int pt   = bid >> 5;          // 0..63 (64 px per block)
    const int b    = pair >> 3;
    const int g    = pair & 7;
    const int tid = threadIdx.x;
    const int lane = tid & 63, wave = tid >> 6;
    const int arow = lane & 15, cgrp = lane >> 4;
    const int px = (pt << 6) + (wave << 4) + arow;
    const int h = px >> 6, w = px & 63;

    // plane-major: pixel stride = 8 elems = 16B
    const __hip_bfloat16* xg   = xt + (((size_t)b * 8 + g) * 4 + cgrp) * CH_HW * 8;
    const __hip_bfloat16* offp = offw + ((size_t)b * 144 + g * 18) * CH_HW + px;
    const __hip_bfloat16* wgb  = dwb + (size_t)g * 9 * 2 * 512 + lane * 8;

    f32x4 acc0 = (f32x4){0.f, 0.f, 0.f, 0.f};
    f32x4 acc1 = (f32x4){0.f, 0.f, 0.f, 0.f};

#pragma unroll
    for (int k = 0; k < 9; ++k) {
        const float oy = __bfloat162float(offp[(size_t)(2 * k) * CH_HW]);
        const float ox = __bfloat162float(offp[(size_t)(2 * k + 1) * CH_HW]);
        const Samp s = make_samp((float)(h - 1 + k / 3) + oy,
                                 (float)(w - 1 + k % 3) + ox);
        const u32x4 cA = *(const u32x4*)(xg + (size_t)s.iA * 8);
        const u32x4 cB = *(const u32x4*)(xg + (size_t)s.iB * 8);
        const u32x4 cC = *(const u32x4*)(xg + (size_t)s.iC * 8);
        const u32x4 cD = *(const u32x4*)(xg + (size_t)s.iD * 8);
        const u32x4 bu0 = *(const u32x4*)(wgb + (size_t)(k * 2 + 0) * 512);
        const u32x4 bu1 = *(const u32x4*)(wgb + (size_t)(k * 2 + 1) * 512);

        float v[8];
#pragma unroll
        for (int qq = 0; qq < 4; ++qq) {
            v[2 * qq] = s.wA * bf16lo(cA[qq]) + s.wB * bf16lo(cB[qq]) +
                        s.wC * bf16lo(cC[qq]) + s.wD * bf16lo(cD[qq]);
            v[2 * qq + 1] = s.wA * bf16hi(cA[qq]) + s.wB * bf16hi(cB[qq]) +
                            s.wC * bf16hi(cC[qq]) + s.wD * bf16hi(cD[qq]);
        }
        const bf16x8 afr = __builtin_bit_cast(bf16x8, pack_bf16x8(v));
        acc0 = __builtin_amdgcn_mfma_f32_16x16x32_bf16(
            afr, __builtin_bit_cast(bf16x8, bu0), acc0, 0, 0, 0);
        acc1 = __builtin_amdgcn_mfma_f32_16x16x32_bf16(
            afr, __builtin_bit_cast(bf16x8, bu1), acc1, 0, 0, 0);
    }

    const int pix4 = (pt << 6) + (wave << 4) + (cgrp << 2);
#pragma unroll
    for (int nt = 0; nt < 2; ++nt) {
        const f32x4 a = nt ? acc1 : acc0;
        const int oc = g * 32 + nt * 16 + arow;
        const float bias = db[oc];
        float4 o4;
        o4.x = a[0] + bias; o4.y = a[1] + bias;
        o4.z = a[2] + bias; o4.w = a[3] + bias;
        *(float4*)&out[((size_t)b * 256 + oc) * CH_HW + pix4] = o4;
    }
}

// ===========================================================================
// Fallback path (round-4 proven, needs only 5.5 MB ws): offs_mfma + deform3
// ===========================================================================
__device__ __forceinline__ void stageA_load(const float* __restrict__ xb,
                                            int hrow, int m, int kc, int ks,
                                            float av[8])
{
    const int tap = ks >> 3, icb = ks & 7;
    const int dy = tap / 3 - 1, dx = tap % 3 - 1;
    const int sh = hrow + dy, sw = m + dx;
    const float msk = (sh >= 0 && sh < 64 && sw >= 0 && sw < 64) ? 1.f : 0.f;
    const int shc = min(max(sh, 0), 63), swc = min(max(sw, 0), 63);
    const float* p = xb + (size_t)(icb * 32 + kc * 8) * CH_HW + (shc << 6) + swc;
#pragma unroll
    for (int j = 0; j < 8; ++j) av[j] = p[(size_t)j * CH_HW] * msk;
}

__global__ __launch_bounds__(256) void offs_mfma(const float* __restrict__ x,
                                                 const __hip_bfloat16* __restrict__ wf,
                                                 const float* __restrict__ ob,
                                                 __hip_bfloat16* __restrict__ offw)
{
    __shared__ __align__(16) unsigned short aL[2][64][40];
    __shared__ __align__(16) unsigned short bL[2][2560];

    const int bid  = blockIdx.x;
    const int nh   = bid & 1;
    const int hrow = (bid >> 1) & 63;
    const int b    = bid >> 7;
    const int ntBase = nh * 5;
    const int NTLOC  = 5 - nh;
    const int tid  = threadIdx.x;
    const int lane = tid & 63, wave = tid >> 6;
    const int m    = lane;
    const int kc   = wave;

    const float* xb = x + (size_t)b * 256 * CH_HW;

    f32x4 acc[5];
#pragma unroll
    for (int q = 0; q < 5; ++q) acc[q] = (f32x4){0.f, 0.f, 0.f, 0.f};

    {
        float av[8]; u32x4 bv[2];
        stageA_load(xb, hrow, m, kc, 0, av);
#pragma unroll
        for (int q = 0; q < 2; ++q) {
            const int ntl = wave + q * 4;
            if (ntl < NTLOC)
                bv[q] = *(const u32x4*)(wf + ((size_t)(ntBase + ntl) * 64 + lane) * 8);
        }
        *(u32x4*)&aL[0][m][kc * 8] = pack_bf16x8(av);
#pragma unroll
        for (int q = 0; q < 2; ++q) {
            const int ntl = wave + q * 4;
            if (ntl < NTLOC) *(u32x4*)&bL[0][ntl * 512 + lane * 8] = bv[q];
        }
    }
    __syncthreads();

    for (int ks = 0; ks < 72; ++ks) {
        const int buf = ks & 1, nbuf = buf ^ 1;
        const bool hasNext = (ks + 1) < 72;

        float av[8]; u32x4 bv[2];
        if (hasNext) {
            stageA_load(xb, hrow, m, kc, ks + 1, av);
#pragma unroll
            for (int q = 0; q < 2; ++q) {
                const int ntl = wave + q * 4;
                if (ntl < NTLOC)
                    bv[q] = *(const u32x4*)(wf + ((size_t)((ks + 1) * 9 + ntBase + ntl) * 64 + lane) * 8);
            }
        }

        const u32x4 au = *(const u32x4*)&aL[buf][wave * 16 + (lane & 15)][(lane >> 4) * 8];
        const bf16x8 afr = __builtin_bit_cast(bf16x8, au);
#pragma unroll
        for (int ntl = 0; ntl < 5; ++ntl) {
            if (ntl < NTLOC) {
                const u32x4 bu = *(const u32x4*)&bL[buf][ntl * 512 + lane * 8];
                acc[ntl] = __builtin_amdgcn_mfma_f32_16x16x32_bf16(
                    afr, __builtin_bit_cast(bf16x8, bu), acc[ntl], 0, 0, 0);
            }
        }

        if (hasNext) {
            *(u32x4*)&aL[nbuf][m][kc * 8] = pack_bf16x8(av);
#pragma unroll
            for (int q = 0; q < 2; ++q) {
                const int ntl = wave + q * 4;
                if (ntl < NTLOC) *(u32x4*)&bL[nbuf][ntl * 512 + lane * 8] = bv[q];
            }
        }
        __syncthreads();
    }

    const int oc_l = lane & 15;
    const int mrow = wave * 16 + ((lane >> 4) << 2);
#pragma unroll
    for (int ntl = 0; ntl < 5; ++ntl) {
        if (ntl < NTLOC) {
            const int oc = (ntBase + ntl) * 16 + oc_l;
            const float bias = ob[oc];
            __hip_bfloat16* op = offw + ((size_t)b * 144 + oc) * CH_HW + hrow * 64 + mrow;
#pragma unroll
            for (int r = 0; r < 4; ++r)
                op[r] = __float2bfloat16(acc[ntl][r] + bias);
        }
    }
}

__global__ __launch_bounds__(256) void deform3(const float* __restrict__ x,
                                               const __hip_bfloat16* __restrict__ offw,
                                               const __hip_bfloat16* __restrict__ dwb,
                                               const float* __restrict__ db,
                                               float* __restrict__ out)
{
    const int pt = blockIdx.x;
    const int g  = blockIdx.y;
    const int b  = blockIdx.z;
    const int tid  = threadIdx.x;
    const int lane = tid & 63, wave = tid >> 6;
    const int pixbase = (pt << 7) + (wave << 5);
    const int arow = lane & 15;
    const int cgrp = lane >> 4;

    const float* xg = x + ((size_t)b * 256 + g * 32 + cgrp * 8) * CH_HW;
    const __hip_bfloat16* offp = offw + ((size_t)b * 144 + g * 18) * CH_HW;
    const __hip_bfloat16* wgb = dwb + (size_t)g * 9 * 2 * 512;

    f32x4 acc[2][2];
#pragma unroll
    for (int mt = 0; mt < 2; ++mt)
#pragma unroll
        for (int nt = 0; nt < 2; ++nt) acc[mt][nt] = (f32x4){0.f, 0.f, 0.f, 0.f};

#pragma unroll 1
    for (int k = 0; k < 9; ++k) {
        const u32x4 bu0 = *(const u32x4*)(wgb + (size_t)(k * 2 + 0) * 512 + lane * 8);
        const u32x4 bu1 = *(const u32x4*)(wgb + (size_t)(k * 2 + 1) * 512 + lane * 8);
        const bf16x8 bf0 = __builtin_bit_cast(bf16x8, bu0);
        const bf16x8 bf1 = __builtin_bit_cast(bf16x8, bu1);
        const int ki = k / 3, kj = k % 3;

#pragma unroll
        for (int mt = 0; mt < 2; ++mt) {
            const int pix = pixbase + mt * 16 + arow;
            const int h = pix >> 6, w = pix & 63;
            const float oy = __bfloat162float(offp[(2 * k) * CH_HW + pix]);
            const float ox = __bfloat162float(offp[(2 * k + 1) * CH_HW + pix]);
            const Samp s = make_samp((float)(h - 1 + ki) + oy,
                                     (float)(w - 1 + kj) + ox);
            float v[8];
#pragma unroll
            for (int j = 0; j < 8; ++j) {
                const float* xc = xg + (size_t)j * CH_HW;
                v[j] = s.wA * xc[s.iA] + s.wB * xc[s.iB] +
                       s.wC * xc[s.iC] + s.wD * xc[s.iD];
            }
            const bf16x8 afr = __builtin_bit_cast(bf16x8, pack_bf16x8(v));
            acc[mt][0] = __builtin_amdgcn_mfma_f32_16x16x32_bf16(afr, bf0, acc[mt][0], 0, 0, 0);
            acc[mt][1] = __builtin_amdgcn_mfma_f32_16x16x32_bf16(afr, bf1, acc[mt][1], 0, 0, 0);
        }
    }

    const int ocl = lane & 15;
#pragma unroll
    for (int mt = 0; mt < 2; ++mt)
#pragma unroll
        for (int nt = 0; nt < 2; ++nt) {
            const int oc = g * 32 + nt * 16 + ocl;
            const float bias = db[oc];
            const int pix = pixbase + mt * 16 + ((lane >> 4) << 2);
            float4 o4;
            o4.x = acc[mt][nt][0] + bias;
            o4.y = acc[mt][nt][1] + bias;
            o4.z = acc[mt][nt][2] + bias;
            o4.w = acc[mt][nt][3] + bias;
            *(float4*)&out[((size_t)b * 256 + oc) * CH_HW + pix] = o4;
        }
}

// ---------------------------------------------------------------------------
extern "C" void kernel_launch(void* const* d_in, const int* in_sizes, int n_in,
                              void* d_out, int out_size, void* d_ws, size_t ws_size,
                              hipStream_t stream) {
    const float* x  = (const float*)d_in[0];
    const float* ow = (const float*)d_in[1];
    const float* ob = (const float*)d_in[2];
    const float* dw = (const float*)d_in[3];
    const float* db = (const float*)d_in[4];
    float* out = (float*)d_out;

    __hip_bfloat16* wf   = (__hip_bfloat16*)d_ws;
    __hip_bfloat16* offw = (__hip_bfloat16*)((char*)d_ws + WF_BYTES);
    __hip_bfloat16* dwb  = (__hip_bfloat16*)((char*)d_ws + WF_BYTES + OFFW_BYTES);
    __hip_bfloat16* xt   = (__hip_bfloat16*)((char*)d_ws + WF_BYTES + OFFW_BYTES + DWB_BYTES);

    const size_t needed = (size_t)WF_BYTES + OFFW_BYTES + DWB_BYTES + XT_BYTES;
    const int nblk = (WF_ELEMS + 255) / 256;   // 1296, covers all three jobs

    if (ws_size >= needed) {
        prep<<<dim3(nblk, 3, 1), 256, 0, stream>>>(ow, dw, x, wf, dwb, xt);
        offs_mfma6<<<1024, 256, 0, stream>>>(xt, wf, ob, offw);
        deform6<<<2048, 256, 0, stream>>>(xt, offw, dwb, db, out);
    } else {
        prep<<<dim3(nblk, 2, 1), 256, 0, stream>>>(ow, dw, x, wf, dwb, xt);
        offs_mfma<<<512, 256, 0, stream>>>(x, wf, ob, offw);
        deform3<<<dim3(32, 8, 4), 256, 0, stream>>>(x, offw, dwb, db, out);
    }
}

// Round 11
// 53.977 us; speedup vs baseline: 1.0608x; 1.0608x over previous
//
#include <hip/hip_runtime.h>
#include <hip/hip_bf16.h>
#include <cstddef>
#include <cstdint>

#define CH_HW 4096   // 64*64

typedef __bf16  bf16x8  __attribute__((ext_vector_type(8)));
typedef float   f32x4   __attribute__((ext_vector_type(4)));
typedef unsigned int u32x4 __attribute__((ext_vector_type(4)));

// d_ws layout (fast path):
//   [0, WF)            bf16 offset-conv weight B-frags
//   [WF, +OFFW)        bf16 offset field
//   [WF+OFFW, +DWB)    bf16 deform weight B-frags
//   [WF+OFFW+DWB,+XT)  bf16 plane-major x: xt[b][g][cgrp][pix][c8]  (16B/px)
#define WF_ELEMS 331776                 // 72 ks * 9 nt * 64 lane * 8
#define WF_BYTES (WF_ELEMS * 2)
#define OFFW_BYTES (4u * 144u * CH_HW * 2u)   // 4,718,592
#define DWB_ELEMS (8 * 9 * 2 * 512)
#define DWB_BYTES (DWB_ELEMS * 2)
#define XT_BYTES ((size_t)4 * 8 * CH_HW * 32 * 2)   // 8,388,608

__device__ __forceinline__ u32x4 pack_bf16x8(const float av[8]) {
    u32x4 ad;
#pragma unroll
    for (int jj = 0; jj < 4; ++jj) {
        const unsigned int lo = __builtin_bit_cast(unsigned short, __float2bfloat16(av[2 * jj]));
        const unsigned int hi = __builtin_bit_cast(unsigned short, __float2bfloat16(av[2 * jj + 1]));
        ad[jj] = lo | (hi << 16);
    }
    return ad;
}
__device__ __forceinline__ float bf16lo(unsigned int u) {
    return __builtin_bit_cast(float, u << 16);
}
__device__ __forceinline__ float bf16hi(unsigned int u) {
    return __builtin_bit_cast(float, u & 0xFFFF0000u);
}

// ---------------------------------------------------------------------------
// Kernel 0 (fused prep): y=0 repack_w, y=1 repack_dwb, y=2 xt_pack
// ---------------------------------------------------------------------------
__global__ __launch_bounds__(256) void prep(const float* __restrict__ ow,
                                            const float* __restrict__ dw,
                                            const float* __restrict__ x,
                                            __hip_bfloat16* __restrict__ wf,
                                            __hip_bfloat16* __restrict__ dwb,
                                            __hip_bfloat16* __restrict__ xt)
{
    const int job = blockIdx.y;
    if (job == 0) {
        const int t = blockIdx.x * 256 + threadIdx.x;
        if (t >= WF_ELEMS) return;
        const int j    = t & 7;
        const int lane = (t >> 3) & 63;
        const int tmp  = t >> 9;
        const int nt   = tmp % 9;
        const int ks   = tmp / 9;
        const int tap  = ks >> 3, icb = ks & 7;
        const int oc   = nt * 16 + (lane & 15);
        const int ic   = icb * 32 + (lane >> 4) * 8 + j;
        wf[t] = __float2bfloat16(ow[(size_t)oc * 2304 + ic * 9 + tap]);
    } else if (job == 1) {
        const int t = blockIdx.x * 256 + threadIdx.x;
        if (t >= DWB_ELEMS) return;
        const int j    = t & 7;
        const int lane = (t >> 3) & 63;
        const int nt   = (t >> 9) & 1;
        const int gk   = t >> 10;
        const int k    = gk % 9;
        const int g    = gk / 9;
        const int oc   = g * 32 + nt * 16 + (lane & 15);
        const int c    = (lane >> 4) * 8 + j;
        dwb[t] = __float2bfloat16(dw[(size_t)oc * 288 + c * 9 + k]);
    } else {
        const int bid = blockIdx.x;
        if (bid >= 512) return;
        const int chunk = bid & 15;
        const int g = (bid >> 4) & 7, b = bid >> 7;
        const int pix = (chunk << 8) + threadIdx.x;
        const float* xs = x + ((size_t)b * 256 + g * 32) * CH_HW + pix;
        __hip_bfloat16* xp = xt + ((size_t)b * 8 + g) * 4 * CH_HW * 8;
#pragma unroll
        for (int q = 0; q < 4; ++q) {
            float av[8];
#pragma unroll
            for (int j = 0; j < 8; ++j) av[j] = xs[(size_t)(q * 8 + j) * CH_HW];
            *(u32x4*)(xp + ((size_t)q * CH_HW + pix) * 8) = pack_bf16x8(av);
        }
    }
}

// ---------------------------------------------------------------------------
// Kernel 1 (fast): offset conv MFMA. Wave = 64 px (4 M-frags) x NT N-frags,
// K-split x4 (4 kh-waves, 18 ks each). Grid 512 (b x hrow x nh), XCD-pinned:
// each XCD owns one (b,nh) -> 360KB B-stream L2-resident. 2 blocks/CU.
// Per K-step per wave: 4 A-loads + NT B-loads + 4*NT MFMA (2-slot pipeline).
// ---------------------------------------------------------------------------
template<int NT>
__device__ __forceinline__ void offs_body7(
    const __hip_bfloat16* __restrict__ xb,   // xt for image b (plane-major)
    const __hip_bfloat16* __restrict__ wfl,  // wf + (ntBase*64+lane)*8
    const float* __restrict__ ob,
    __hip_bfloat16* __restrict__ offw_b,     // offw for image b
    float* __restrict__ red,                 // LDS: 3 regions x 1024*NT floats
    int hrow, int lane, int ntBase, int kh)
{
    const int arow = lane & 15, cgrp = lane >> 4;
    const int ks0 = kh * 18;

    auto loadA1 = [&](int ks, int mt) -> u32x4 {
        const int tap = ks >> 3, icb = ks & 7;
        const int dy = tap / 3 - 1, dx = tap % 3 - 1;
        const int sh = hrow + dy, sw = mt * 16 + arow + dx;
        const bool valid = (sh >= 0) & (sh < 64) & (sw >= 0) & (sw < 64);
        const int spix = (min(max(sh, 0), 63) << 6) + min(max(sw, 0), 63);
        u32x4 a = *(const u32x4*)(xb + ((size_t)(icb * 4 + cgrp) * CH_HW + spix) * 8);
        if (!valid) a = (u32x4){0, 0, 0, 0};
        return a;
    };

    f32x4 acc[4][NT];
#pragma unroll
    for (int mt = 0; mt < 4; ++mt)
#pragma unroll
        for (int nt = 0; nt < NT; ++nt) acc[mt][nt] = (f32x4){0.f, 0.f, 0.f, 0.f};

    u32x4 a0[4], a1[4], b0[NT], b1[NT];
#pragma unroll
    for (int mt = 0; mt < 4; ++mt) {
        a0[mt] = loadA1(ks0 + 0, mt);
        a1[mt] = loadA1(ks0 + 1, mt);
    }
#pragma unroll
    for (int nt = 0; nt < NT; ++nt) {
        b0[nt] = *(const u32x4*)(wfl + (size_t)((ks0 + 0) * 9 + nt) * 512);
        b1[nt] = *(const u32x4*)(wfl + (size_t)((ks0 + 1) * 9 + nt) * 512);
    }

    // 8 branch-free iterations (consume pair i,i+1; refill i+2,i+3)
#pragma unroll 1
    for (int i = 0; i < 16; i += 2) {
        const int ks = ks0 + i;
#pragma unroll
        for (int mt = 0; mt < 4; ++mt) {
            const bf16x8 af = __builtin_bit_cast(bf16x8, a0[mt]);
#pragma unroll
            for (int nt = 0; nt < NT; ++nt)
                acc[mt][nt] = __builtin_amdgcn_mfma_f32_16x16x32_bf16(
                    af, __builtin_bit_cast(bf16x8, b0[nt]), acc[mt][nt], 0, 0, 0);
        }
#pragma unroll
        for (int mt = 0; mt < 4; ++mt) a0[mt] = loadA1(ks + 2, mt);
#pragma unroll
        for (int nt = 0; nt < NT; ++nt)
            b0[nt] = *(const u32x4*)(wfl + (size_t)((ks + 2) * 9 + nt) * 512);
#pragma unroll
        for (int mt = 0; mt < 4; ++mt) {
            const bf16x8 af = __builtin_bit_cast(bf16x8, a1[mt]);
#pragma unroll
            for (int nt = 0; nt < NT; ++nt)
                acc[mt][nt] = __builtin_amdgcn_mfma_f32_16x16x32_bf16(
                    af, __builtin_bit_cast(bf16x8, b1[nt]), acc[mt][nt], 0, 0, 0);
        }
#pragma unroll
        for (int mt = 0; mt < 4; ++mt) a1[mt] = loadA1(ks + 3, mt);
#pragma unroll
        for (int nt = 0; nt < NT; ++nt)
            b1[nt] = *(const u32x4*)(wfl + (size_t)((ks + 3) * 9 + nt) * 512);
    }
    // peeled tail: consume last pair (ks0+16, ks0+17)
#pragma unroll
    for (int mt = 0; mt < 4; ++mt) {
        const bf16x8 af = __builtin_bit_cast(bf16x8, a0[mt]);
#pragma unroll
        for (int nt = 0; nt < NT; ++nt)
            acc[mt][nt] = __builtin_amdgcn_mfma_f32_16x16x32_bf16(
                af, __builtin_bit_cast(bf16x8, b0[nt]), acc[mt][nt], 0, 0, 0);
    }
#pragma unroll
    for (int mt = 0; mt < 4; ++mt) {
        const bf16x8 af = __builtin_bit_cast(bf16x8, a1[mt]);
#pragma unroll
        for (int nt = 0; nt < NT; ++nt)
            acc[mt][nt] = __builtin_amdgcn_mfma_f32_16x16x32_bf16(
                af, __builtin_bit_cast(bf16x8, b1[nt]), acc[mt][nt], 0, 0, 0);
    }

    // 4-way K reduction: kh 1..3 dump, barrier, kh0 reduces + stores
    const int RSTRIDE = 1024 * NT;   // floats per region
    if (kh > 0) {
        float* r = red + (kh - 1) * RSTRIDE;
#pragma unroll
        for (int mt = 0; mt < 4; ++mt)
#pragma unroll
            for (int nt = 0; nt < NT; ++nt)
                *(f32x4*)&r[((mt * NT + nt) * 64 + lane) * 4] = acc[mt][nt];
    }
    __syncthreads();
    if (kh == 0) {
#pragma unroll
        for (int mt = 0; mt < 4; ++mt) {
            const int pxb = hrow * 64 + mt * 16 + (cgrp << 2);
#pragma unroll
            for (int nt = 0; nt < NT; ++nt) {
                const int ri = ((mt * NT + nt) * 64 + lane) * 4;
                const f32x4 p1 = *(const f32x4*)&red[ri];
                const f32x4 p2 = *(const f32x4*)&red[RSTRIDE + ri];
                const f32x4 p3 = *(const f32x4*)&red[2 * RSTRIDE + ri];
                const int oc = (ntBase + nt) * 16 + arow;
                const float bias = ob[oc];
                float av[4];
#pragma unroll
                for (int r4 = 0; r4 < 4; ++r4)
                    av[r4] = acc[mt][nt][r4] + p1[r4] + p2[r4] + p3[r4] + bias;
                unsigned int q0 = (unsigned int)__builtin_bit_cast(unsigned short, __float2bfloat16(av[0])) |
                                  ((unsigned int)__builtin_bit_cast(unsigned short, __float2bfloat16(av[1])) << 16);
                unsigned int q1 = (unsigned int)__builtin_bit_cast(unsigned short, __float2bfloat16(av[2])) |
                                  ((unsigned int)__builtin_bit_cast(unsigned short, __float2bfloat16(av[3])) << 16);
                unsigned int* op = (unsigned int*)(offw_b + (size_t)oc * CH_HW + pxb);
                op[0] = q0; op[1] = q1;
            }
        }
    }
}

__global__ __launch_bounds__(256, 2) void offs_mfma7(
    const __hip_bfloat16* __restrict__ xt,
    const __hip_bfloat16* __restrict__ wf,
    const float* __restrict__ ob,
    __hip_bfloat16* __restrict__ offw)
{
    __shared__ float red[15360];              // 3 regions x up to 5120 floats
    const int bid  = blockIdx.x;              // 0..511
    const int xcd  = bid & 7;
    const int b    = xcd >> 1;                // 2 XCDs per batch image
    const int half = xcd & 1;                 // nh half, pinned per XCD
    const int q    = bid >> 3;                // 0..63
    const int hrow = q;
    const int nh   = half;
    const int tid  = threadIdx.x;
    const int lane = tid & 63, kh = tid >> 6;
    const int ntBase = nh * 5;

    const __hip_bfloat16* xb  = xt + (size_t)b * 8 * CH_HW * 32;
    const __hip_bfloat16* wfl = wf + (size_t)(ntBase * 64 + lane) * 8;
    __hip_bfloat16* offw_b = offw + (size_t)b * 144 * CH_HW;

    if (nh == 0) offs_body7<5>(xb, wfl, ob, offw_b, red, hrow, lane, ntBase, kh);
    else         offs_body7<4>(xb, wfl, ob, offw_b, red, hrow, lane, ntBase, kh);
}

// ---------------------------------------------------------------------------
// Kernel 2 (fast): bilinear sampling (plane-major xt, 16B pixel stride) +
// grouped-conv MFMA. 1-D grid XCD-pinned: wgid = pt*32 + (g+8b).
// ---------------------------------------------------------------------------
struct Samp { int iA, iB, iC, iD; float wA, wB, wC, wD; };

__device__ __forceinline__ Samp make_samp(float py, float px) {
    const float y0f = floorf(py), x0f = floorf(px);
    const int iy0 = (int)y0f, ix0 = (int)x0f;
    const int iy1 = iy0 + 1,  ix1 = ix0 + 1;
    const float fy1 = py - y0f, fx1 = px - x0f;
    const float fy0 = 1.f - fy1, fx0 = 1.f - fx1;
    const bool vy0 = (iy0 >= 0) & (iy0 < 64);
    const bool vy1 = (iy1 >= 0) & (iy1 < 64);
    const bool vx0 = (ix0 >= 0) & (ix0 < 64);
    const bool vx1 = (ix1 >= 0) & (ix1 < 64);
    const int cy0 = min(max(iy0, 0), 63), cy1 = min(max(iy1, 0), 63);
    const int cx0 = min(max(ix0, 0), 63), cx1 = min(max(ix1, 0), 63);
    Samp s;
    s.iA = (cy0 << 6) + cx0; s.iB = (cy0 << 6) + cx1;
    s.iC = (cy1 << 6) + cx0; s.iD = (cy1 << 6) + cx1;
    s.wA = (vy0 & vx0) ? fy0 * fx0 : 0.f;
    s.wB = (vy0 & vx1) ? fy0 * fx1 : 0.f;
    s.wC = (vy1 & vx0) ? fy1 * fx0 : 0.f;
    s.wD = (vy1 & vx1) ? fy1 * fx1 : 0.f;
    return s;
}

__global__ __launch_bounds__(256, 4) void deform6(
    const __hip_bfloat16* __restrict__ xt,
    const __hip_bfloat16* __restrict__ offw,
    const __hip_bfloat16* __restrict__ dwb,
    const float* __restrict__ db,
    float* __restrict__ out)
{
    const int bid  = blockIdx.x;        // 0..2047
    const int pair = bid & 31;          // g + 8*b  -> XCD = pair % 8
    const int pt   = bid >> 5;          // 0..63 (64 px per block)
    const int b    = pair >> 3;
    const int g    = pair & 7;
    const int tid = threadIdx.x;
    const int lane = tid & 63, wave = tid >> 6;
    const int arow = lane & 15, cgrp = lane >> 4;
    const int px = (pt << 6) + (wave << 4) + arow;
    const int h = px >> 6, w = px & 63;

    // plane-major: pixel stride = 8 elems = 16B
    const __hip_bfloat16* xg   = xt + (((size_t)b * 8 + g) * 4 + cgrp) * CH_HW * 8;
    const __hip_bfloat16* offp = offw + ((size_t)b * 144 + g * 18) * CH_HW + px;
    const __hip_bfloat16* wgb  = dwb + (size_t)g * 9 * 2 * 512 + lane * 8;

    f32x4 acc0 = (f32x4){0.f, 0.f, 0.f, 0.f};
    f32x4 acc1 = (f32x4){0.f, 0.f, 0.f, 0.f};

#pragma unroll
    for (int k = 0; k < 9; ++k) {
        const float oy = __bfloat162float(offp[(size_t)(2 * k) * CH_HW]);
        const float ox = __bfloat162float(offp[(size_t)(2 * k + 1) * CH_HW]);
        const Samp s = make_samp((float)(h - 1 + k / 3) + oy,
                                 (float)(w - 1 + k % 3) + ox);
        const u32x4 cA = *(const u32x4*)(xg + (size_t)s.iA * 8);
        const u32x4 cB = *(const u32x4*)(xg + (size_t)s.iB * 8);
        const u32x4 cC = *(const u32x4*)(xg + (size_t)s.iC * 8);
        const u32x4 cD = *(const u32x4*)(xg + (size_t)s.iD * 8);
        const u32x4 bu0 = *(const u32x4*)(wgb + (size_t)(k * 2 + 0) * 512);
        const u32x4 bu1 = *(const u32x4*)(wgb + (size_t)(k * 2 + 1) * 512);

        float v[8];
#pragma unroll
        for (int qq = 0; qq < 4; ++qq) {
            v[2 * qq] = s.wA * bf16lo(cA[qq]) + s.wB * bf16lo(cB[qq]) +
                        s.wC * bf16lo(cC[qq]) + s.wD * bf16lo(cD[qq]);
            v[2 * qq + 1] = s.wA * bf16hi(cA[qq]) + s.wB * bf16hi(cB[qq]) +
                            s.wC * bf16hi(cC[qq]) + s.wD * bf16hi(cD[qq]);
        }
        const bf16x8 afr = __builtin_bit_cast(bf16x8, pack_bf16x8(v));
        acc0 = __builtin_amdgcn_mfma_f32_16x16x32_bf16(
            afr, __builtin_bit_cast(bf16x8, bu0), acc0, 0, 0, 0);
        acc1 = __builtin_amdgcn_mfma_f32_16x16x32_bf16(
            afr, __builtin_bit_cast(bf16x8, bu1), acc1, 0, 0, 0);
    }

    const int pix4 = (pt << 6) + (wave << 4) + (cgrp << 2);
#pragma unroll
    for (int nt = 0; nt < 2; ++nt) {
        const f32x4 a = nt ? acc1 : acc0;
        const int oc = g * 32 + nt * 16 + arow;
        const float bias = db[oc];
        float4 o4;
        o4.x = a[0] + bias; o4.y = a[1] + bias;
        o4.z = a[2] + bias; o4.w = a[3] + bias;
        *(float4*)&out[((size_t)b * 256 + oc) * CH_HW + pix4] = o4;
    }
}

// ===========================================================================
// Fallback path (round-4 proven, needs only 5.5 MB ws): offs_mfma + deform3
// ===========================================================================
__device__ __forceinline__ void stageA_load(const float* __restrict__ xb,
                                            int hrow, int m, int kc, int ks,
                                            float av[8])
{
    const int tap = ks >> 3, icb = ks & 7;
    const int dy = tap / 3 - 1, dx = tap % 3 - 1;
    const int sh = hrow + dy, sw = m + dx;
    const float msk = (sh >= 0 && sh < 64 && sw >= 0 && sw < 64) ? 1.f : 0.f;
    const int shc = min(max(sh, 0), 63), swc = min(max(sw, 0), 63);
    const float* p = xb + (size_t)(icb * 32 + kc * 8) * CH_HW + (shc << 6) + swc;
#pragma unroll
    for (int j = 0; j < 8; ++j) av[j] = p[(size_t)j * CH_HW] * msk;
}

__global__ __launch_bounds__(256) void offs_mfma(const float* __restrict__ x,
                                                 const __hip_bfloat16* __restrict__ wf,
                                                 const float* __restrict__ ob,
                                                 __hip_bfloat16* __restrict__ offw)
{
    __shared__ __align__(16) unsigned short aL[2][64][40];
    __shared__ __align__(16) unsigned short bL[2][2560];

    const int bid  = blockIdx.x;
    const int nh   = bid & 1;
    const int hrow = (bid >> 1) & 63;
    const int b    = bid >> 7;
    const int ntBase = nh * 5;
    const int NTLOC  = 5 - nh;
    const int tid  = threadIdx.x;
    const int lane = tid & 63, wave = tid >> 6;
    const int m    = lane;
    const int kc   = wave;

    const float* xb = x + (size_t)b * 256 * CH_HW;

    f32x4 acc[5];
#pragma unroll
    for (int q = 0; q < 5; ++q) acc[q] = (f32x4){0.f, 0.f, 0.f, 0.f};

    {
        float av[8]; u32x4 bv[2];
        stageA_load(xb, hrow, m, kc, 0, av);
#pragma unroll
        for (int q = 0; q < 2; ++q) {
            const int ntl = wave + q * 4;
            if (ntl < NTLOC)
                bv[q] = *(const u32x4*)(wf + ((size_t)(ntBase + ntl) * 64 + lane) * 8);
        }
        *(u32x4*)&aL[0][m][kc * 8] = pack_bf16x8(av);
#pragma unroll
        for (int q = 0; q < 2; ++q) {
            const int ntl = wave + q * 4;
            if (ntl < NTLOC) *(u32x4*)&bL[0][ntl * 512 + lane * 8] = bv[q];
        }
    }
    __syncthreads();

    for (int ks = 0; ks < 72; ++ks) {
        const int buf = ks & 1, nbuf = buf ^ 1;
        const bool hasNext = (ks + 1) < 72;

        float av[8]; u32x4 bv[2];
        if (hasNext) {
            stageA_load(xb, hrow, m, kc, ks + 1, av);
#pragma unroll
            for (int q = 0; q < 2; ++q) {
                const int ntl = wave + q * 4;
                if (ntl < NTLOC)
                    bv[q] = *(const u32x4*)(wf + ((size_t)((ks + 1) * 9 + ntBase + ntl) * 64 + lane) * 8);
            }
        }

        const u32x4 au = *(const u32x4*)&aL[buf][wave * 16 + (lane & 15)][(lane >> 4) * 8];
        const bf16x8 afr = __builtin_bit_cast(bf16x8, au);
#pragma unroll
        for (int ntl = 0; ntl < 5; ++ntl) {
            if (ntl < NTLOC) {
                const u32x4 bu = *(const u32x4*)&bL[buf][ntl * 512 + lane * 8];
                acc[ntl] = __builtin_amdgcn_mfma_f32_16x16x32_bf16(
                    afr, __builtin_bit_cast(bf16x8, bu), acc[ntl], 0, 0, 0);
            }
        }

        if (hasNext) {
            *(u32x4*)&aL[nbuf][m][kc * 8] = pack_bf16x8(av);
#pragma unroll
            for (int q = 0; q < 2; ++q) {
                const int ntl = wave + q * 4;
                if (ntl < NTLOC) *(u32x4*)&bL[nbuf][ntl * 512 + lane * 8] = bv[q];
            }
        }
        __syncthreads();
    }

    const int oc_l = lane & 15;
    const int mrow = wave * 16 + ((lane >> 4) << 2);
#pragma unroll
    for (int ntl = 0; ntl < 5; ++ntl) {
        if (ntl < NTLOC) {
            const int oc = (ntBase + ntl) * 16 + oc_l;
            const float bias = ob[oc];
            __hip_bfloat16* op = offw + ((size_t)b * 144 + oc) * CH_HW + hrow * 64 + mrow;
#pragma unroll
            for (int r = 0; r < 4; ++r)
                op[r] = __float2bfloat16(acc[ntl][r] + bias);
        }
    }
}

__global__ __launch_bounds__(256) void deform3(const float* __restrict__ x,
                                               const __hip_bfloat16* __restrict__ offw,
                                               const __hip_bfloat16* __restrict__ dwb,
                                               const float* __restrict__ db,
                                               float* __restrict__ out)
{
    const int pt = blockIdx.x;
    const int g  = blockIdx.y;
    const int b  = blockIdx.z;
    const int tid  = threadIdx.x;
    const int lane = tid & 63, wave = tid >> 6;
    const int pixbase = (pt << 7) + (wave << 5);
    const int arow = lane & 15;
    const int cgrp = lane >> 4;

    const float* xg = x + ((size_t)b * 256 + g * 32 + cgrp * 8) * CH_HW;
    const __hip_bfloat16* offp = offw + ((size_t)b * 144 + g * 18) * CH_HW;
    const __hip_bfloat16* wgb = dwb + (size_t)g * 9 * 2 * 512;

    f32x4 acc[2][2];
#pragma unroll
    for (int mt = 0; mt < 2; ++mt)
#pragma unroll
        for (int nt = 0; nt < 2; ++nt) acc[mt][nt] = (f32x4){0.f, 0.f, 0.f, 0.f};

#pragma unroll 1
    for (int k = 0; k < 9; ++k) {
        const u32x4 bu0 = *(const u32x4*)(wgb + (size_t)(k * 2 + 0) * 512 + lane * 8);
        const u32x4 bu1 = *(const u32x4*)(wgb + (size_t)(k * 2 + 1) * 512 + lane * 8);
        const bf16x8 bf0 = __builtin_bit_cast(bf16x8, bu0);
        const bf16x8 bf1 = __builtin_bit_cast(bf16x8, bu1);
        const int ki = k / 3, kj = k % 3;

#pragma unroll
        for (int mt = 0; mt < 2; ++mt) {
            const int pix = pixbase + mt * 16 + arow;
            const int h = pix >> 6, w = pix & 63;
            const float oy = __bfloat162float(offp[(2 * k) * CH_HW + pix]);
            const float ox = __bfloat162float(offp[(2 * k + 1) * CH_HW + pix]);
            const Samp s = make_samp((float)(h - 1 + ki) + oy,
                                     (float)(w - 1 + kj) + ox);
            float v[8];
#pragma unroll
            for (int j = 0; j < 8; ++j) {
                const float* xc = xg + (size_t)j * CH_HW;
                v[j] = s.wA * xc[s.iA] + s.wB * xc[s.iB] +
                       s.wC * xc[s.iC] + s.wD * xc[s.iD];
            }
            const bf16x8 afr = __builtin_bit_cast(bf16x8, pack_bf16x8(v));
            acc[mt][0] = __builtin_amdgcn_mfma_f32_16x16x32_bf16(afr, bf0, acc[mt][0], 0, 0, 0);
            acc[mt][1] = __builtin_amdgcn_mfma_f32_16x16x32_bf16(afr, bf1, acc[mt][1], 0, 0, 0);
        }
    }

    const int ocl = lane & 15;
#pragma unroll
    for (int mt = 0; mt < 2; ++mt)
#pragma unroll
        for (int nt = 0; nt < 2; ++nt) {
            const int oc = g * 32 + nt * 16 + ocl;
            const float bias = db[oc];
            const int pix = pixbase + mt * 16 + ((lane >> 4) << 2);
            float4 o4;
            o4.x = acc[mt][nt][0] + bias;
            o4.y = acc[mt][nt][1] + bias;
            o4.z = acc[mt][nt][2] + bias;
            o4.w = acc[mt][nt][3] + bias;
            *(float4*)&out[((size_t)b * 256 + oc) * CH_HW + pix] = o4;
        }
}

// ---------------------------------------------------------------------------
extern "C" void kernel_launch(void* const* d_in, const int* in_sizes, int n_in,
                              void* d_out, int out_size, void* d_ws, size_t ws_size,
                              hipStream_t stream) {
    const float* x  = (const float*)d_in[0];
    const float* ow = (const float*)d_in[1];
    const float* ob = (const float*)d_in[2];
    const float* dw = (const float*)d_in[3];
    const float* db = (const float*)d_in[4];
    float* out = (float*)d_out;

    __hip_bfloat16* wf   = (__hip_bfloat16*)d_ws;
    __hip_bfloat16* offw = (__hip_bfloat16*)((char*)d_ws + WF_BYTES);
    __hip_bfloat16* dwb  = (__hip_bfloat16*)((char*)d_ws + WF_BYTES + OFFW_BYTES);
    __hip_bfloat16* xt   = (__hip_bfloat16*)((char*)d_ws + WF_BYTES + OFFW_BYTES + DWB_BYTES);

    const size_t needed = (size_t)WF_BYTES + OFFW_BYTES + DWB_BYTES + XT_BYTES;
    const int nblk = (WF_ELEMS + 255) / 256;   // 1296, covers all three jobs

    if (ws_size >= needed) {
        prep<<<dim3(nblk, 3, 1), 256, 0, stream>>>(ow, dw, x, wf, dwb, xt);
        offs_mfma7<<<512, 256, 0, stream>>>(xt, wf, ob, offw);
        deform6<<<2048, 256, 0, stream>>>(xt, offw, dwb, db, out);
    } else {
        prep<<<dim3(nblk, 2, 1), 256, 0, stream>>>(ow, dw, x, wf, dwb, xt);
        offs_mfma<<<512, 256, 0, stream>>>(x, wf, ob, offw);
        deform3<<<dim3(32, 8, 4), 256, 0, stream>>>(x, offw, dwb, db, out);
    }
}

// Round 12
// 52.513 us; speedup vs baseline: 1.0904x; 1.0279x over previous
//
#include <hip/hip_runtime.h>
#include <hip/hip_bf16.h>
#include <cstddef>
#include <cstdint>

#define CH_HW 4096   // 64*64

typedef __bf16  bf16x8  __attribute__((ext_vector_type(8)));
typedef float   f32x4   __attribute__((ext_vector_type(4)));
typedef unsigned int u32x4 __attribute__((ext_vector_type(4)));

// d_ws layout (fast path):
//   [0, WF)            bf16 offset-conv weight B-frags
//   [WF, +OFFW)        bf16 offset field, interleaved offw2[(b*8+g)][px][18]
//   [WF+OFFW, +DWB)    bf16 deform weight B-frags
//   [WF+OFFW+DWB,+XT)  bf16 plane-major x: xt[b][g][cgrp][pix][c8]  (16B/px)
#define WF_ELEMS 331776                 // 72 ks * 9 nt * 64 lane * 8
#define WF_BYTES (WF_ELEMS * 2)
#define OFFW_BYTES (4u * 144u * CH_HW * 2u)   // 4,718,592 (same size, new layout)
#define DWB_ELEMS (8 * 9 * 2 * 512)
#define DWB_BYTES (DWB_ELEMS * 2)
#define XT_BYTES ((size_t)4 * 8 * CH_HW * 32 * 2)   // 8,388,608

__device__ __forceinline__ u32x4 pack_bf16x8(const float av[8]) {
    u32x4 ad;
#pragma unroll
    for (int jj = 0; jj < 4; ++jj) {
        const unsigned int lo = __builtin_bit_cast(unsigned short, __float2bfloat16(av[2 * jj]));
        const unsigned int hi = __builtin_bit_cast(unsigned short, __float2bfloat16(av[2 * jj + 1]));
        ad[jj] = lo | (hi << 16);
    }
    return ad;
}
__device__ __forceinline__ float bf16lo(unsigned int u) {
    return __builtin_bit_cast(float, u << 16);
}
__device__ __forceinline__ float bf16hi(unsigned int u) {
    return __builtin_bit_cast(float, u & 0xFFFF0000u);
}

// ---------------------------------------------------------------------------
// Kernel 0 (fused prep): y=0 repack_w, y=1 repack_dwb, y=2 xt_pack
// ---------------------------------------------------------------------------
__global__ __launch_bounds__(256) void prep(const float* __restrict__ ow,
                                            const float* __restrict__ dw,
                                            const float* __restrict__ x,
                                            __hip_bfloat16* __restrict__ wf,
                                            __hip_bfloat16* __restrict__ dwb,
                                            __hip_bfloat16* __restrict__ xt)
{
    const int job = blockIdx.y;
    if (job == 0) {
        const int t = blockIdx.x * 256 + threadIdx.x;
        if (t >= WF_ELEMS) return;
        const int j    = t & 7;
        const int lane = (t >> 3) & 63;
        const int tmp  = t >> 9;
        const int nt   = tmp % 9;
        const int ks   = tmp / 9;
        const int tap  = ks >> 3, icb = ks & 7;
        const int oc   = nt * 16 + (lane & 15);
        const int ic   = icb * 32 + (lane >> 4) * 8 + j;
        wf[t] = __float2bfloat16(ow[(size_t)oc * 2304 + ic * 9 + tap]);
    } else if (job == 1) {
        const int t = blockIdx.x * 256 + threadIdx.x;
        if (t >= DWB_ELEMS) return;
        const int j    = t & 7;
        const int lane = (t >> 3) & 63;
        const int nt   = (t >> 9) & 1;
        const int gk   = t >> 10;
        const int k    = gk % 9;
        const int g    = gk / 9;
        const int oc   = g * 32 + nt * 16 + (lane & 15);
        const int c    = (lane >> 4) * 8 + j;
        dwb[t] = __float2bfloat16(dw[(size_t)oc * 288 + c * 9 + k]);
    } else {
        const int bid = blockIdx.x;
        if (bid >= 512) return;
        const int chunk = bid & 15;
        const int g = (bid >> 4) & 7, b = bid >> 7;
        const int pix = (chunk << 8) + threadIdx.x;
        const float* xs = x + ((size_t)b * 256 + g * 32) * CH_HW + pix;
        __hip_bfloat16* xp = xt + ((size_t)b * 8 + g) * 4 * CH_HW * 8;
#pragma unroll
        for (int q = 0; q < 4; ++q) {
            float av[8];
#pragma unroll
            for (int j = 0; j < 8; ++j) av[j] = xs[(size_t)(q * 8 + j) * CH_HW];
            *(u32x4*)(xp + ((size_t)q * CH_HW + pix) * 8) = pack_bf16x8(av);
        }
    }
}

// ---------------------------------------------------------------------------
// Kernel 1 (fast): offset conv MFMA (r11 structure). Wave = 64 px x NT,
// K-split x4. Grid 512, XCD-pinned. Epilogue writes INTERLEAVED offw2:
// offw2[(b*8+g)*4096 + px)*18 + (oc%18)]  (g = oc/18).
// ---------------------------------------------------------------------------
template<int NT>
__device__ __forceinline__ void offs_body7(
    const __hip_bfloat16* __restrict__ xb,
    const __hip_bfloat16* __restrict__ wfl,
    const float* __restrict__ ob,
    __hip_bfloat16* __restrict__ offw2_b,    // offw2 for image b: + b*8*4096*18
    float* __restrict__ red,
    int hrow, int lane, int ntBase, int kh)
{
    const int arow = lane & 15, cgrp = lane >> 4;
    const int ks0 = kh * 18;

    auto loadA1 = [&](int ks, int mt) -> u32x4 {
        const int tap = ks >> 3, icb = ks & 7;
        const int dy = tap / 3 - 1, dx = tap % 3 - 1;
        const int sh = hrow + dy, sw = mt * 16 + arow + dx;
        const bool valid = (sh >= 0) & (sh < 64) & (sw >= 0) & (sw < 64);
        const int spix = (min(max(sh, 0), 63) << 6) + min(max(sw, 0), 63);
        u32x4 a = *(const u32x4*)(xb + ((size_t)(icb * 4 + cgrp) * CH_HW + spix) * 8);
        if (!valid) a = (u32x4){0, 0, 0, 0};
        return a;
    };

    f32x4 acc[4][NT];
#pragma unroll
    for (int mt = 0; mt < 4; ++mt)
#pragma unroll
        for (int nt = 0; nt < NT; ++nt) acc[mt][nt] = (f32x4){0.f, 0.f, 0.f, 0.f};

    u32x4 a0[4], a1[4], b0[NT], b1[NT];
#pragma unroll
    for (int mt = 0; mt < 4; ++mt) {
        a0[mt] = loadA1(ks0 + 0, mt);
        a1[mt] = loadA1(ks0 + 1, mt);
    }
#pragma unroll
    for (int nt = 0; nt < NT; ++nt) {
        b0[nt] = *(const u32x4*)(wfl + (size_t)((ks0 + 0) * 9 + nt) * 512);
        b1[nt] = *(const u32x4*)(wfl + (size_t)((ks0 + 1) * 9 + nt) * 512);
    }

#pragma unroll 1
    for (int i = 0; i < 16; i += 2) {
        const int ks = ks0 + i;
#pragma unroll
        for (int mt = 0; mt < 4; ++mt) {
            const bf16x8 af = __builtin_bit_cast(bf16x8, a0[mt]);
#pragma unroll
            for (int nt = 0; nt < NT; ++nt)
                acc[mt][nt] = __builtin_amdgcn_mfma_f32_16x16x32_bf16(
                    af, __builtin_bit_cast(bf16x8, b0[nt]), acc[mt][nt], 0, 0, 0);
        }
#pragma unroll
        for (int mt = 0; mt < 4; ++mt) a0[mt] = loadA1(ks + 2, mt);
#pragma unroll
        for (int nt = 0; nt < NT; ++nt)
            b0[nt] = *(const u32x4*)(wfl + (size_t)((ks + 2) * 9 + nt) * 512);
#pragma unroll
        for (int mt = 0; mt < 4; ++mt) {
            const bf16x8 af = __builtin_bit_cast(bf16x8, a1[mt]);
#pragma unroll
            for (int nt = 0; nt < NT; ++nt)
                acc[mt][nt] = __builtin_amdgcn_mfma_f32_16x16x32_bf16(
                    af, __builtin_bit_cast(bf16x8, b1[nt]), acc[mt][nt], 0, 0, 0);
        }
#pragma unroll
        for (int mt = 0; mt < 4; ++mt) a1[mt] = loadA1(ks + 3, mt);
#pragma unroll
        for (int nt = 0; nt < NT; ++nt)
            b1[nt] = *(const u32x4*)(wfl + (size_t)((ks + 3) * 9 + nt) * 512);
    }
#pragma unroll
    for (int mt = 0; mt < 4; ++mt) {
        const bf16x8 af = __builtin_bit_cast(bf16x8, a0[mt]);
#pragma unroll
        for (int nt = 0; nt < NT; ++nt)
            acc[mt][nt] = __builtin_amdgcn_mfma_f32_16x16x32_bf16(
                af, __builtin_bit_cast(bf16x8, b0[nt]), acc[mt][nt], 0, 0, 0);
    }
#pragma unroll
    for (int mt = 0; mt < 4; ++mt) {
        const bf16x8 af = __builtin_bit_cast(bf16x8, a1[mt]);
#pragma unroll
        for (int nt = 0; nt < NT; ++nt)
            acc[mt][nt] = __builtin_amdgcn_mfma_f32_16x16x32_bf16(
                af, __builtin_bit_cast(bf16x8, b1[nt]), acc[mt][nt], 0, 0, 0);
    }

    const int RSTRIDE = 1024 * NT;
    if (kh > 0) {
        float* r = red + (kh - 1) * RSTRIDE;
#pragma unroll
        for (int mt = 0; mt < 4; ++mt)
#pragma unroll
            for (int nt = 0; nt < NT; ++nt)
                *(f32x4*)&r[((mt * NT + nt) * 64 + lane) * 4] = acc[mt][nt];
    }
    __syncthreads();
    if (kh == 0) {
#pragma unroll
        for (int mt = 0; mt < 4; ++mt) {
            const int pxb = hrow * 64 + mt * 16 + (cgrp << 2);
#pragma unroll
            for (int nt = 0; nt < NT; ++nt) {
                const int ri = ((mt * NT + nt) * 64 + lane) * 4;
                const f32x4 p1 = *(const f32x4*)&red[ri];
                const f32x4 p2 = *(const f32x4*)&red[RSTRIDE + ri];
                const f32x4 p3 = *(const f32x4*)&red[2 * RSTRIDE + ri];
                const int oc = (ntBase + nt) * 16 + arow;
                const int g  = oc / 18;
                const int ocl = oc - g * 18;
                const float bias = ob[oc];
                __hip_bfloat16* op = offw2_b + ((size_t)g * CH_HW + pxb) * 18 + ocl;
#pragma unroll
                for (int r4 = 0; r4 < 4; ++r4) {
                    const float v = acc[mt][nt][r4] + p1[r4] + p2[r4] + p3[r4] + bias;
                    op[(size_t)r4 * 18] = __float2bfloat16(v);
                }
            }
        }
    }
}

__global__ __launch_bounds__(256, 2) void offs_mfma7(
    const __hip_bfloat16* __restrict__ xt,
    const __hip_bfloat16* __restrict__ wf,
    const float* __restrict__ ob,
    __hip_bfloat16* __restrict__ offw2)
{
    __shared__ float red[15360];
    const int bid  = blockIdx.x;              // 0..511
    const int xcd  = bid & 7;
    const int b    = xcd >> 1;
    const int half = xcd & 1;
    const int hrow = bid >> 3;                // 0..63
    const int nh   = half;
    const int tid  = threadIdx.x;
    const int lane = tid & 63, kh = tid >> 6;
    const int ntBase = nh * 5;

    const __hip_bfloat16* xb  = xt + (size_t)b * 8 * CH_HW * 32;
    const __hip_bfloat16* wfl = wf + (size_t)(ntBase * 64 + lane) * 8;
    __hip_bfloat16* offw2_b = offw2 + (size_t)b * 8 * CH_HW * 18;

    if (nh == 0) offs_body7<5>(xb, wfl, ob, offw2_b, red, hrow, lane, ntBase, kh);
    else         offs_body7<4>(xb, wfl, ob, offw2_b, red, hrow, lane, ntBase, kh);
}

// ---------------------------------------------------------------------------
// Kernel 2 (fast): deform7 — 2 px/thread (B-frags shared across 2 M-frags),
// interleaved offset loads (36B contiguous per px: 3 vector loads).
// Grid 1024 XCD-pinned: wgid = pt*32 + (g+8b). (256,4) -> 4 blocks/CU.
// ---------------------------------------------------------------------------
struct Samp { int iA, iB, iC, iD; float wA, wB, wC, wD; };

__device__ __forceinline__ Samp make_samp(float py, float px) {
    const float y0f = floorf(py), x0f = floorf(px);
    const int iy0 = (int)y0f, ix0 = (int)x0f;
    const int iy1 = iy0 + 1,  ix1 = ix0 + 1;
    const float fy1 = py - y0f, fx1 = px - x0f;
    const float fy0 = 1.f - fy1, fx0 = 1.f - fx1;
    const bool vy0 = (iy0 >= 0) & (iy0 < 64);
    const bool vy1 = (iy1 >= 0) & (iy1 < 64);
    const bool vx0 = (ix0 >= 0) & (ix0 < 64);
    const bool vx1 = (ix1 >= 0) & (ix1 < 64);
    const int cy0 = min(max(iy0, 0), 63), cy1 = min(max(iy1, 0), 63);
    const int cx0 = min(max(ix0, 0), 63), cx1 = min(max(ix1, 0), 63);
    Samp s;
    s.iA = (cy0 << 6) + cx0; s.iB = (cy0 << 6) + cx1;
    s.iC = (cy1 << 6) + cx0; s.iD = (cy1 << 6) + cx1;
    s.wA = (vy0 & vx0) ? fy0 * fx0 : 0.f;
    s.wB = (vy0 & vx1) ? fy0 * fx1 : 0.f;
    s.wC = (vy1 & vx0) ? fy1 * fx0 : 0.f;
    s.wD = (vy1 & vx1) ? fy1 * fx1 : 0.f;
    return s;
}

__device__ __forceinline__ f32x4 bilin8(const __hip_bfloat16* xg, const Samp& s,
                                        const bf16x8 bfr0, const bf16x8 bfr1,
                                        f32x4 acc0, f32x4 acc1, f32x4* acc1out)
{
    const u32x4 cA = *(const u32x4*)(xg + (size_t)s.iA * 8);
    const u32x4 cB = *(const u32x4*)(xg + (size_t)s.iB * 8);
    const u32x4 cC = *(const u32x4*)(xg + (size_t)s.iC * 8);
    const u32x4 cD = *(const u32x4*)(xg + (size_t)s.iD * 8);
    float v[8];
#pragma unroll
    for (int qq = 0; qq < 4; ++qq) {
        v[2 * qq] = s.wA * bf16lo(cA[qq]) + s.wB * bf16lo(cB[qq]) +
                    s.wC * bf16lo(cC[qq]) + s.wD * bf16lo(cD[qq]);
        v[2 * qq + 1] = s.wA * bf16hi(cA[qq]) + s.wB * bf16hi(cB[qq]) +
                        s.wC * bf16hi(cC[qq]) + s.wD * bf16hi(cD[qq]);
    }
    const bf16x8 afr = __builtin_bit_cast(bf16x8, pack_bf16x8(v));
    acc0 = __builtin_amdgcn_mfma_f32_16x16x32_bf16(afr, bfr0, acc0, 0, 0, 0);
    *acc1out = __builtin_amdgcn_mfma_f32_16x16x32_bf16(afr, bfr1, acc1, 0, 0, 0);
    return acc0;
}

__global__ __launch_bounds__(256, 4) void deform7(
    const __hip_bfloat16* __restrict__ xt,
    const __hip_bfloat16* __restrict__ offw2,
    const __hip_bfloat16* __restrict__ dwb,
    const float* __restrict__ db,
    float* __restrict__ out)
{
    const int bid  = blockIdx.x;        // 0..1023
    const int pair = bid & 31;          // g + 8*b  -> XCD = pair % 8
    const int pt   = bid >> 5;          // 0..31 (128 px per block)
    const int b    = pair >> 3;
    const int g    = pair & 7;
    const int tid = threadIdx.x;
    const int lane = tid & 63, wave = tid >> 6;
    const int arow = lane & 15, cgrp = lane >> 4;
    const int wbase = (pt << 7) + (wave << 5);  // wave's 32 px
    const int px0 = wbase + arow;
    const int px1 = wbase + 16 + arow;
    const int h0 = px0 >> 6, w0 = px0 & 63;
    const int h1 = px1 >> 6, w1 = px1 & 63;

    const __hip_bfloat16* xg  = xt + (((size_t)b * 8 + g) * 4 + cgrp) * CH_HW * 8;
    const __hip_bfloat16* wgb = dwb + (size_t)g * 9 * 2 * 512 + lane * 8;
    const __hip_bfloat16* obase = offw2 + ((size_t)b * 8 + g) * CH_HW * 18;

    // interleaved offsets: 18 bf16 = 36B contiguous per px -> 2x dwordx4 + 1 dword
    unsigned int po0[9], po1[9];
    {
        const unsigned int* p0 = (const unsigned int*)(obase + (size_t)px0 * 18);
        const unsigned int* p1 = (const unsigned int*)(obase + (size_t)px1 * 18);
        const u32x4 a0 = *(const u32x4*)p0;
        const u32x4 a1 = *(const u32x4*)(p0 + 4);
        const unsigned int a2 = p0[8];
        const u32x4 c0 = *(const u32x4*)p1;
        const u32x4 c1 = *(const u32x4*)(p1 + 4);
        const unsigned int c2 = p1[8];
#pragma unroll
        for (int k = 0; k < 4; ++k) { po0[k] = a0[k]; po0[k + 4] = a1[k]; }
        po0[8] = a2;
#pragma unroll
        for (int k = 0; k < 4; ++k) { po1[k] = c0[k]; po1[k + 4] = c1[k]; }
        po1[8] = c2;
    }

    f32x4 acc[2][2];
#pragma unroll
    for (int mt = 0; mt < 2; ++mt)
#pragma unroll
        for (int nt = 0; nt < 2; ++nt) acc[mt][nt] = (f32x4){0.f, 0.f, 0.f, 0.f};

#pragma unroll
    for (int k = 0; k < 9; ++k) {
        const bf16x8 bfr0 = __builtin_bit_cast(bf16x8,
            *(const u32x4*)(wgb + (size_t)(k * 2 + 0) * 512));
        const bf16x8 bfr1 = __builtin_bit_cast(bf16x8,
            *(const u32x4*)(wgb + (size_t)(k * 2 + 1) * 512));
        const int ki = k / 3, kj = k % 3;

        const Samp s0 = make_samp((float)(h0 - 1 + ki) + bf16lo(po0[k]),
                                  (float)(w0 - 1 + kj) + bf16hi(po0[k]));
        acc[0][0] = bilin8(xg, s0, bfr0, bfr1, acc[0][0], acc[0][1], &acc[0][1]);

        const Samp s1 = make_samp((float)(h1 - 1 + ki) + bf16lo(po1[k]),
                                  (float)(w1 - 1 + kj) + bf16hi(po1[k]));
        acc[1][0] = bilin8(xg, s1, bfr0, bfr1, acc[1][0], acc[1][1], &acc[1][1]);
    }

#pragma unroll
    for (int mt = 0; mt < 2; ++mt) {
        const int pix4 = wbase + mt * 16 + (cgrp << 2);
#pragma unroll
        for (int nt = 0; nt < 2; ++nt) {
            const f32x4 a = acc[mt][nt];
            const int oc = g * 32 + nt * 16 + arow;
            const float bias = db[oc];
            float4 o4;
            o4.x = a[0] + bias; o4.y = a[1] + bias;
            o4.z = a[2] + bias; o4.w = a[3] + bias;
            *(float4*)&out[((size_t)b * 256 + oc) * CH_HW + pix4] = o4;
        }
    }
}

// ===========================================================================
// Fallback path (round-4 proven, needs only 5.5 MB ws): offs_mfma + deform3
// (internally consistent old offw layout)
// ===========================================================================
__device__ __forceinline__ void stageA_load(const float* __restrict__ xb,
                                            int hrow, int m, int kc, int ks,
                                            float av[8])
{
    const int tap = ks >> 3, icb = ks & 7;
    const int dy = tap / 3 - 1, dx = tap % 3 - 1;
    const int sh = hrow + dy, sw = m + dx;
    const float msk = (sh >= 0 && sh < 64 && sw >= 0 && sw < 64) ? 1.f : 0.f;
    const int shc = min(max(sh, 0), 63), swc = min(max(sw, 0), 63);
    const float* p = xb + (size_t)(icb * 32 + kc * 8) * CH_HW + (shc << 6) + swc;
#pragma unroll
    for (int j = 0; j < 8; ++j) av[j] = p[(size_t)j * CH_HW] * msk;
}

__global__ __launch_bounds__(256) void offs_mfma(const float* __restrict__ x,
                                                 const __hip_bfloat16* __restrict__ wf,
                                                 const float* __restrict__ ob,
                                                 __hip_bfloat16* __restrict__ offw)
{
    __shared__ __align__(16) unsigned short aL[2][64][40];
    __shared__ __align__(16) unsigned short bL[2][2560];

    const int bid  = blockIdx.x;
    const int nh   = bid & 1;
    const int hrow = (bid >> 1) & 63;
    const int b    = bid >> 7;
    const int ntBase = nh * 5;
    const int NTLOC  = 5 - nh;
    const int tid  = threadIdx.x;
    const int lane = tid & 63, wave = tid >> 6;
    const int m    = lane;
    const int kc   = wave;

    const float* xb = x + (size_t)b * 256 * CH_HW;

    f32x4 acc[5];
#pragma unroll
    for (int q = 0; q < 5; ++q) acc[q] = (f32x4){0.f, 0.f, 0.f, 0.f};

    {
        float av[8]; u32x4 bv[2];
        stageA_load(xb, hrow, m, kc, 0, av);
#pragma unroll
        for (int q = 0; q < 2; ++q) {
            const int ntl = wave + q * 4;
            if (ntl < NTLOC)
                bv[q] = *(const u32x4*)(wf + ((size_t)(ntBase + ntl) * 64 + lane) * 8);
        }
        *(u32x4*)&aL[0][m][kc * 8] = pack_bf16x8(av);
#pragma unroll
        for (int q = 0; q < 2; ++q) {
            const int ntl = wave + q * 4;
            if (ntl < NTLOC) *(u32x4*)&bL[0][ntl * 512 + lane * 8] = bv[q];
        }
    }
    __syncthreads();

    for (int ks = 0; ks < 72; ++ks) {
        const int buf = ks & 1, nbuf = buf ^ 1;
        const bool hasNext = (ks + 1) < 72;

        float av[8]; u32x4 bv[2];
        if (hasNext) {
            stageA_load(xb, hrow, m, kc, ks + 1, av);
#pragma unroll
            for (int q = 0; q < 2; ++q) {
                const int ntl = wave + q * 4;
                if (ntl < NTLOC)
                    bv[q] = *(const u32x4*)(wf + ((size_t)((ks + 1) * 9 + ntBase + ntl) * 64 + lane) * 8);
            }
        }

        const u32x4 au = *(const u32x4*)&aL[buf][wave * 16 + (lane & 15)][(lane >> 4) * 8];
        const bf16x8 afr = __builtin_bit_cast(bf16x8, au);
#pragma unroll
        for (int ntl = 0; ntl < 5; ++ntl) {
            if (ntl < NTLOC) {
                const u32x4 bu = *(const u32x4*)&bL[buf][ntl * 512 + lane * 8];
                acc[ntl] = __builtin_amdgcn_mfma_f32_16x16x32_bf16(
                    afr, __builtin_bit_cast(bf16x8, bu), acc[ntl], 0, 0, 0);
            }
        }

        if (hasNext) {
            *(u32x4*)&aL[nbuf][m][kc * 8] = pack_bf16x8(av);
#pragma unroll
            for (int q = 0; q < 2; ++q) {
                const int ntl = wave + q * 4;
                if (ntl < NTLOC) *(u32x4*)&bL[nbuf][ntl * 512 + lane * 8] = bv[q];
            }
        }
        __syncthreads();
    }

    const int oc_l = lane & 15;
    const int mrow = wave * 16 + ((lane >> 4) << 2);
#pragma unroll
    for (int ntl = 0; ntl < 5; ++ntl) {
        if (ntl < NTLOC) {
            const int oc = (ntBase + ntl) * 16 + oc_l;
            const float bias = ob[oc];
            __hip_bfloat16* op = offw + ((size_t)b * 144 + oc) * CH_HW + hrow * 64 + mrow;
#pragma unroll
            for (int r = 0; r < 4; ++r)
                op[r] = __float2bfloat16(acc[ntl][r] + bias);
        }
    }
}

__global__ __launch_bounds__(256) void deform3(const float* __restrict__ x,
                                               const __hip_bfloat16* __restrict__ offw,
                                               const __hip_bfloat16* __restrict__ dwb,
                                               const float* __restrict__ db,
                                               float* __restrict__ out)
{
    const int pt = blockIdx.x;
    const int g  = blockIdx.y;
    const int b  = blockIdx.z;
    const int tid  = threadIdx.x;
    const int lane = tid & 63, wave = tid >> 6;
    const int pixbase = (pt << 7) + (wave << 5);
    const int arow = lane & 15;
    const int cgrp = lane >> 4;

    const float* xg = x + ((size_t)b * 256 + g * 32 + cgrp * 8) * CH_HW;
    const __hip_bfloat16* offp = offw + ((size_t)b * 144 + g * 18) * CH_HW;
    const __hip_bfloat16* wgb = dwb + (size_t)g * 9 * 2 * 512;

    f32x4 acc[2][2];
#pragma unroll
    for (int mt = 0; mt < 2; ++mt)
#pragma unroll
        for (int nt = 0; nt < 2; ++nt) acc[mt][nt] = (f32x4){0.f, 0.f, 0.f, 0.f};

#pragma unroll 1
    for (int k = 0; k < 9; ++k) {
        const u32x4 bu0 = *(const u32x4*)(wgb + (size_t)(k * 2 + 0) * 512 + lane * 8);
        const u32x4 bu1 = *(const u32x4*)(wgb + (size_t)(k * 2 + 1) * 512 + lane * 8);
        const bf16x8 bf0 = __builtin_bit_cast(bf16x8, bu0);
        const bf16x8 bf1 = __builtin_bit_cast(bf16x8, bu1);
        const int ki = k / 3, kj = k % 3;

#pragma unroll
        for (int mt = 0; mt < 2; ++mt) {
            const int pix = pixbase + mt * 16 + arow;
            const int h = pix >> 6, w = pix & 63;
            const float oy = __bfloat162float(offp[(2 * k) * CH_HW + pix]);
            const float ox = __bfloat162float(offp[(2 * k + 1) * CH_HW + pix]);
            const Samp s = make_samp((float)(h - 1 + ki) + oy,
                                     (float)(w - 1 + kj) + ox);
            float v[8];
#pragma unroll
            for (int j = 0; j < 8; ++j) {
                const float* xc = xg + (size_t)j * CH_HW;
                v[j] = s.wA * xc[s.iA] + s.wB * xc[s.iB] +
                       s.wC * xc[s.iC] + s.wD * xc[s.iD];
            }
            const bf16x8 afr = __builtin_bit_cast(bf16x8, pack_bf16x8(v));
            acc[mt][0] = __builtin_amdgcn_mfma_f32_16x16x32_bf16(afr, bf0, acc[mt][0], 0, 0, 0);
            acc[mt][1] = __builtin_amdgcn_mfma_f32_16x16x32_bf16(afr, bf1, acc[mt][1], 0, 0, 0);
        }
    }

    const int ocl = lane & 15;
#pragma unroll
    for (int mt = 0; mt < 2; ++mt)
#pragma unroll
        for (int nt = 0; nt < 2; ++nt) {
            const int oc = g * 32 + nt * 16 + ocl;
            const float bias = db[oc];
            const int pix = pixbase + mt * 16 + ((lane >> 4) << 2);
            float4 o4;
            o4.x = acc[mt][nt][0] + bias;
            o4.y = acc[mt][nt][1] + bias;
            o4.z = acc[mt][nt][2] + bias;
            o4.w = acc[mt][nt][3] + bias;
            *(float4*)&out[((size_t)b * 256 + oc) * CH_HW + pix] = o4;
        }
}

// ---------------------------------------------------------------------------
extern "C" void kernel_launch(void* const* d_in, const int* in_sizes, int n_in,
                              void* d_out, int out_size, void* d_ws, size_t ws_size,
                              hipStream_t stream) {
    const float* x  = (const float*)d_in[0];
    const float* ow = (const float*)d_in[1];
    const float* ob = (const float*)d_in[2];
    const float* dw = (const float*)d_in[3];
    const float* db = (const float*)d_in[4];
    float* out = (float*)d_out;

    __hip_bfloat16* wf   = (__hip_bfloat16*)d_ws;
    __hip_bfloat16* offw = (__hip_bfloat16*)((char*)d_ws + WF_BYTES);
    __hip_bfloat16* dwb  = (__hip_bfloat16*)((char*)d_ws + WF_BYTES + OFFW_BYTES);
    __hip_bfloat16* xt   = (__hip_bfloat16*)((char*)d_ws + WF_BYTES + OFFW_BYTES + DWB_BYTES);

    const size_t needed = (size_t)WF_BYTES + OFFW_BYTES + DWB_BYTES + XT_BYTES;
    const int nblk = (WF_ELEMS + 255) / 256;   // 1296, covers all three jobs

    if (ws_size >= needed) {
        prep<<<dim3(nblk, 3, 1), 256, 0, stream>>>(ow, dw, x, wf, dwb, xt);
        offs_mfma7<<<512, 256, 0, stream>>>(xt, wf, ob, offw);
        deform7<<<1024, 256, 0, stream>>>(xt, offw, dwb, db, out);
    } else {
        prep<<<dim3(nblk, 2, 1), 256, 0, stream>>>(ow, dw, x, wf, dwb, xt);
        offs_mfma<<<512, 256, 0, stream>>>(x, wf, ob, offw);
        deform3<<<dim3(32, 8, 4), 256, 0, stream>>>(x, offw, dwb, db, out);
    }
}